// Round 17
// baseline (448.610 us; speedup 1.0000x reference)
//
#include <hip/hip_runtime.h>
#include <cstdint>
#include <cstddef>

// ---------------- problem constants ----------------
#define NEXP   32          // routed experts
#define TOPK   4
#define HD     1024        // hidden
#define ID     512         // intermediate
#define TT     4096        // tokens (B*S)
#define CAP    1024        // capacity per routed expert
#define SHARED_BASE (NEXP*CAP)        // 32768 : slot base of shared-expert rows
#define NSLOT  (NEXP*CAP + TT)        // 36864 total slot rows
#define MAXTILES 320       // grid-y: (qy>>3) up to 40 >= worst chunk 36

#define KSPLIT 16          // router split-K
#define KCH    64          // K per logits block
#define KSUB   16          // LDS sub-chunk

#define BSTR   40          // Bs row stride (elems): 80B -> bank-rich (R16)

typedef __attribute__((ext_vector_type(4))) float f32x4;
typedef __bf16 bf16x8 __attribute__((ext_vector_type(8)));

__device__ __forceinline__ unsigned short f2bf(float f) {
    union { float f; unsigned int u; } v; v.f = f;
    unsigned int u = v.u;
    u = (u + 0x7FFFu + ((u >> 16) & 1u)) >> 16;   // RNE
    return (unsigned short)u;
}
__device__ __forceinline__ float bf2f(unsigned short s) {
    union { unsigned int u; float f; } v; v.u = ((unsigned int)s) << 16;
    return v.f;
}

#define GLOAD_LDS16(g, l)                                                     \
    __builtin_amdgcn_global_load_lds(                                         \
        (__attribute__((address_space(1))) void*)(g),                         \
        (__attribute__((address_space(3))) void*)(l), 16, 0, 0)

// ---------------- router logits (split-K) + fused x->bf16 convert ---------
__global__ __launch_bounds__(256)
void k_logits(const float* __restrict__ x, const float* __restrict__ gw,
              float* __restrict__ part, unsigned short* __restrict__ xb) {
    __shared__ float xsT[KSUB][260];
    __shared__ float gsT[KSUB][36];
    const int tid = threadIdx.x;
    const int lane = tid & 63, wv = tid >> 6;
    const int tg = lane >> 2, eg = lane & 3;
    const int t0 = blockIdx.x * 256;
    const int kbase = blockIdx.y * KCH;
    const int tbase = wv * 64 + tg * 4;
    const int ebase = eg * 8;

    float acc[4][8];
#pragma unroll
    for (int j = 0; j < 4; j++)
#pragma unroll
        for (int i = 0; i < 8; i++) acc[j][i] = 0.f;

    for (int ks = 0; ks < KCH; ks += KSUB) {
        const int k0 = kbase + ks;
        if (ks > 0) __syncthreads();
        // stage x sub-chunk [256 t][16 k] (+ bf16 copy); 2-way banks (free)
#pragma unroll
        for (int p = 0; p < 4; p++) {
            int vid = p * 256 + tid;
            int t = vid >> 2, kq = (vid & 3) * 4;
            float4 v = *(const float4*)(x + (size_t)(t0 + t) * HD + k0 + kq);
            xsT[kq + 0][t] = v.x; xsT[kq + 1][t] = v.y;
            xsT[kq + 2][t] = v.z; xsT[kq + 3][t] = v.w;
            ushort4 o;
            o.x = f2bf(v.x); o.y = f2bf(v.y); o.z = f2bf(v.z); o.w = f2bf(v.w);
            *(ushort4*)(xb + (size_t)(t0 + t) * HD + k0 + kq) = o;
        }
#pragma unroll
        for (int p = 0; p < 2; p++) {
            int vid = p * 256 + tid;
            int e = vid >> 4, k = vid & 15;
            gsT[k][e] = gw[(size_t)e * HD + k0 + k];
        }
        __syncthreads();
#pragma unroll 4
        for (int k = 0; k < KSUB; k++) {
            float4 xv = *(const float4*)&xsT[k][tbase];
            float4 g0 = *(const float4*)&gsT[k][ebase];
            float4 g1 = *(const float4*)&gsT[k][ebase + 4];
            float xa[4] = {xv.x, xv.y, xv.z, xv.w};
#pragma unroll
            for (int j = 0; j < 4; j++) {
                acc[j][0] += xa[j] * g0.x; acc[j][1] += xa[j] * g0.y;
                acc[j][2] += xa[j] * g0.z; acc[j][3] += xa[j] * g0.w;
                acc[j][4] += xa[j] * g1.x; acc[j][5] += xa[j] * g1.y;
                acc[j][6] += xa[j] * g1.z; acc[j][7] += xa[j] * g1.w;
            }
        }
    }
    const size_t base = ((size_t)blockIdx.y * TT + (t0 + tbase)) * 32 + ebase;
#pragma unroll
    for (int j = 0; j < 4; j++) {
        float4 w0, w1;
        w0.x = acc[j][0]; w0.y = acc[j][1]; w0.z = acc[j][2]; w0.w = acc[j][3];
        w1.x = acc[j][4]; w1.y = acc[j][5]; w1.z = acc[j][6]; w1.w = acc[j][7];
        *(float4*)(part + base + (size_t)j * 32) = w0;
        *(float4*)(part + base + (size_t)j * 32 + 4) = w1;
    }
}

// ---------------- router part 2: reduce partials, top-4 (NO atomics) ------
__global__ __launch_bounds__(256)
void k_topk(const float* __restrict__ part,
            int* __restrict__ choice, float* __restrict__ cw,
            int* __restrict__ tok, float* __restrict__ wgt) {
    const int lane = threadIdx.x & 63, wv = threadIdx.x >> 6;
    const int t = blockIdx.x * 4 + wv;
    const int e = lane & 31;
    const int sbase = (lane >> 5) * 8;
    float v = 0.f;
#pragma unroll
    for (int s = 0; s < 8; s++)
        v += part[((size_t)(sbase + s) * TT + t) * 32 + e];
    v += __shfl_xor(v, 32);
    float sc = (lane < 32) ? v : -INFINITY;

    float lv[TOPK]; int le[TOPK];
#pragma unroll
    for (int r = 0; r < TOPK; r++) {
        float m = sc;
#pragma unroll
        for (int d = 1; d < 64; d <<= 1) m = fmaxf(m, __shfl_xor(m, d));
        unsigned long long ball = __ballot(sc == m);
        int widx = __ffsll(ball) - 1;       // lowest lane on tie = jax top_k
        lv[r] = m; le[r] = widx;
        if (lane == widx) sc = -INFINITY;
    }
    if (lane == 0) {
        float wv4[TOPK], wsum = 0.f;
#pragma unroll
        for (int r = 0; r < TOPK; r++) { wv4[r] = __expf(lv[r] - lv[0]); wsum += wv4[r]; }
#pragma unroll
        for (int r = 0; r < TOPK; r++) {
            choice[t * TOPK + r] = le[r];
            cw[t * TOPK + r] = wv4[r] / wsum;
        }
        tok[SHARED_BASE + t] = t;            // shared-expert identity slot
        wgt[SHARED_BASE + t] = 1.0f;
    }
}

// ---------------- slot assignment: token-granular ballot-scan -------------
__global__ __launch_bounds__(1024)
void k_assign(const int* __restrict__ choice, const float* __restrict__ cw,
              int* __restrict__ cnt, int* __restrict__ tok,
              float* __restrict__ wgt, int* __restrict__ smap) {
    const int e = blockIdx.x;
    const int tid = threadIdx.x, lane = tid & 63, wv = tid >> 6;
    __shared__ int wtot[16];
    int running = 0;
    for (int it = 0; it < TT / 1024; it++) {       // 4 iterations
        const int t = it * 1024 + tid;             // token id
        const int4   c4 = *(const int4*)(choice + t * 4);
        const float4 w4 = *(const float4*)(cw + t * 4);
        unsigned m = (unsigned)(c4.x == e) | ((unsigned)(c4.y == e) << 1)
                   | ((unsigned)(c4.z == e) << 2) | ((unsigned)(c4.w == e) << 3);
        int mc = __popc(m);
        int pre = mc;                              // inclusive wave scan
#pragma unroll
        for (int d = 1; d < 64; d <<= 1) {
            int up = __shfl_up(pre, d);
            if (lane >= d) pre += up;
        }
        if (lane == 63) wtot[wv] = pre;            // wave total
        const int wpre = pre - mc;                 // exclusive within wave
        __syncthreads();
        int woff = 0, tot = 0;
#pragma unroll
        for (int w = 0; w < 16; w++) { int c = wtot[w]; tot += c; if (w < wv) woff += c; }
        int base = running + woff + wpre;
        running += tot;
        __syncthreads();
        if (m) {
            const float wa[4] = {w4.x, w4.y, w4.z, w4.w};
            int k = 0;
#pragma unroll
            for (int r = 0; r < 4; r++) {
                if (m & (1u << r)) {
                    int pos = base + k;
                    int i = t * 4 + r;
                    if (pos < CAP) {
                        int slot = e * CAP + pos;
                        tok[slot] = t;
                        wgt[slot] = wa[r];
                        smap[i] = slot;
                    } else {
                        smap[i] = -1;              // overflow dropped (P ~ 0)
                    }
                    k++;
                }
            }
        }
    }
    if (tid == 0) cnt[e] = min(running, CAP);
}

// ---------------- grouped GEMM: 128x128 tile, BK=32 ----------------------
// R17: B register pipeline deepened to 2 iters (two named float4 sets,
// parity-static). R16 gave B(it+1) only one MFMA phase (~300-600 cyc) to
// cover ~900 cyc HBM latency -> BPACK stalled every iter (dur flat at 130us
// while conflicts halved). Now iter it loads B(it+2) into set(it&1) and
// packs B(it+1) from the other set -> ~1 full iter of cover.
// Queue trace (steady state, oldest->newest at top of iter it):
//   [A(it) 2, B(it+1) 4, A(it+1) 2] -> wait vmcnt(6) drains A(it), leaves 6.
//   (BPACK at iter it-1 drained through B(it); verified for it=0,1,2.)
//   Last iter: vmcnt(0). BPACK waits are compiler-tracked register deps.
// BSTR=40 + extended slot XOR F(r)=((r>>2)&3)^((r>>4)&3) kept (4-way writes).
// LDS 24 + 20.5 = 44.5 KB; +16 VGPR (second F set) -> ~160/wave, still
// 3 waves/SIMD.
template <int KD, bool GATHER, bool SILU>
__global__ __launch_bounds__(256)
void k_moe_gemm(const unsigned short* __restrict__ Ab,
                const float* __restrict__ Bf,
                const float* __restrict__ BfS,
                unsigned short* __restrict__ Cout,
                const int* __restrict__ tok,
                const int* __restrict__ cnt) {
    const int tid  = threadIdx.x;
    const int lane = tid & 63;
    const int wv   = tid >> 6;

    // ---- in-kernel tile table ----
    int c_l = (lane < NEXP) ? min(cnt[lane], CAP) : ((lane == NEXP) ? TT : 0);
    int nt_l = (c_l + 127) >> 7;
    int pre = nt_l;
#pragma unroll
    for (int d = 1; d < 64; d <<= 1) {
        int up = __shfl_up(pre, d);
        if (lane >= d) pre += up;
    }
    const int ntl = __shfl(pre, 63);
    const int chunk = (ntl + 7) >> 3;
    const int c_xcd = blockIdx.x;
    const int qy = blockIdx.y;
    if ((qy >> 3) >= chunk) return;
    const int j = c_xcd * chunk + (qy >> 3);
    if (j >= ntl) return;
    const int nt = qy & 7;
    const int start_l = pre - nt_l;
    const bool mine = (j >= start_l) && (j < start_l + nt_l);
    const unsigned long long bl = __ballot(mine);
    const int e_lane = __ffsll((long long)bl) - 1;
    const int e  = e_lane;
    const int mt = j - __shfl(start_l, e_lane);
    const int cE = __shfl(c_l, e_lane);

    const int slotbase = (e < NEXP) ? e * CAP : SHARED_BASE;
    const int m0 = mt * 128;
    const int rowsv = min(128, cE - m0);

    const float* Btf = (e < NEXP) ? Bf + (size_t)e * ((size_t)KD * 1024) : BfS;

    __shared__ unsigned short As[3][128 * 32];   // 24 KB
    __shared__ unsigned short Bs[2][128 * BSTR]; // 20.5 KB

    // ---- A staging (gload_lds; swizzle s^((r>>2)&3) on lane map) ----
    const int rr   = lane >> 2;
    const int segA = (lane & 3) ^ ((lane >> 4) & 3);
    const int r0 = wv * 32 + rr;
    const int r1 = r0 + 16;

    int ga0 = m0 + r0, ga1 = m0 + r1;
    int ra0, ra1;
    if (GATHER) {
        ra0 = (ga0 < cE) ? tok[slotbase + ga0] : 0;
        ra1 = (ga1 < cE) ? tok[slotbase + ga1] : 0;
    } else {
        ra0 = slotbase + ga0;
        ra1 = slotbase + ga1;
    }
    const unsigned short* ap0 = Ab + (size_t)ra0 * KD + segA * 8;
    const unsigned short* ap1 = Ab + (size_t)ra1 * KD + segA * 8;
    const int aoff0 = (wv * 32) * 32, aoff1 = (wv * 32 + 16) * 32;

    // ---- B staging lane map: hB = lane>>5, nw = lane&31 (4-col window) ----
    const int hB = lane >> 5;                 // k-half within wave's 8 rows
    const int nw = lane & 31;                 // col window: 4 cols
    int rB[4], offB[4];
    int bcol;
    if (SILU) {
        const int sn0 = nw * 4;
        const int side = sn0 >> 6;            // window never straddles 64
        const int jj0 = sn0 & 63;
        bcol = (side ? 512 : 0) + nt * 64 + jj0;
#pragma unroll
        for (int q = 0; q < 4; q++) {
            int jj = jj0 + q;
            rB[q] = ((jj >> 5) << 6) + (side << 5) + (jj & 31);
        }
    } else {
        bcol = nt * 128 + nw * 4;
#pragma unroll
        for (int q = 0; q < 4; q++) rB[q] = nw * 4 + q;
    }
#pragma unroll
    for (int q = 0; q < 4; q++) {
        int slotW = wv ^ ((rB[q] >> 2) & 3) ^ ((rB[q] >> 4) & 3);
        offB[q] = rB[q] * BSTR + slotW * 8 + hB * 4;   // elems; 8B-aligned
    }
    // global src base: fp32 rows (k0 + wv*8 + hB*4 + d), stride 1024 floats
    const float* bpf = Btf + (size_t)(wv * 8 + hB * 4) * 1024 + bcol;

    float4 Fa0, Fa1, Fa2, Fa3;    // B reg set a (even B-chunks)
    float4 Fb0, Fb1, Fb2, Fb3;    // B reg set b (odd B-chunks)
#define BLOADS(IT, S0, S1, S2, S3)                                            \
    {                                                                         \
        const float* bpk = bpf + (size_t)(IT) * 32 * 1024;                    \
        S0 = *(const float4*)(bpk);                                           \
        S1 = *(const float4*)(bpk + 1024);                                    \
        S2 = *(const float4*)(bpk + 2048);                                    \
        S3 = *(const float4*)(bpk + 3072);                                    \
    }
#define BPACKS(BUF, S0, S1, S2, S3)                                           \
    {                                                                         \
        unsigned short* bw = &Bs[BUF][0];                                     \
        const float* a0p = (const float*)&S0;                                 \
        const float* a1p = (const float*)&S1;                                 \
        const float* a2p = (const float*)&S2;                                 \
        const float* a3p = (const float*)&S3;                                 \
        _Pragma("unroll")                                                     \
        for (int q = 0; q < 4; q++) {                                         \
            unsigned lo, hi;                                                  \
            asm("v_cvt_pk_bf16_f32 %0, %1, %2"                                \
                : "=v"(lo) : "v"(a0p[q]), "v"(a1p[q]));                       \
            asm("v_cvt_pk_bf16_f32 %0, %1, %2"                                \
                : "=v"(hi) : "v"(a2p[q]), "v"(a3p[q]));                       \
            uint2 wv2; wv2.x = lo; wv2.y = hi;                                \
            *(uint2*)(bw + offB[q]) = wv2;                                    \
        }                                                                     \
    }

    f32x4 acc[4][4];
#pragma unroll
    for (int i = 0; i < 4; i++)
#pragma unroll
        for (int j2 = 0; j2 < 4; j2++) acc[i][j2] = (f32x4)(0.0f);

    const int mrow = lane & 15;
    const int quad = lane >> 4;
    const int wm = wv >> 1, wn = wv & 1;
    const int swA = (quad ^ ((mrow >> 2) & 3)) * 8;      // A read slot
    const int aRdOff = (wm * 64 + mrow) * 32 + swA;
    const int bRdBase = (wn * 64 + mrow) * BSTR;         // B read base (row part)
    const int slotB0 = quad ^ ((mrow >> 2) & 3);         // B slot before i-term

    const int NIT = KD / 32;

    // ---- prologue: B(0)->Fa, A(0),A(1) gloads, pack B(0), B(1)->Fb ----
    BLOADS(0, Fa0, Fa1, Fa2, Fa3);
    __builtin_amdgcn_sched_barrier(0);
    GLOAD_LDS16(ap0, As[0] + aoff0);
    GLOAD_LDS16(ap1, As[0] + aoff1);
    GLOAD_LDS16(ap0 + 32, As[1] + aoff0);
    GLOAD_LDS16(ap1 + 32, As[1] + aoff1);
    __builtin_amdgcn_sched_barrier(0);
    BPACKS(0, Fa0, Fa1, Fa2, Fa3);   // waits B(0) only; A stays in flight
    BLOADS(1, Fb0, Fb1, Fb2, Fb3);   // B(1) in flight across iter 0

#define GITER(IT, RBUF, L0, L1, L2, L3, P0, P1, P2, P3)                       \
    {                                                                         \
        if ((IT) < NIT - 1)                                                   \
            asm volatile("s_waitcnt vmcnt(6) lgkmcnt(0)" ::: "memory");       \
        else                                                                  \
            asm volatile("s_waitcnt vmcnt(0) lgkmcnt(0)" ::: "memory");       \
        __builtin_amdgcn_s_barrier();                                         \
        asm volatile("" ::: "memory");                                        \
        const bool has2 = (IT) + 2 < NIT;                                     \
        if (has2) BLOADS((IT) + 2, L0, L1, L2, L3);                           \
        __builtin_amdgcn_sched_barrier(0);                                    \
        if (has2) {                                                           \
            int pw = pA + 2; if (pw >= 3) pw -= 3;                            \
            GLOAD_LDS16(ap0 + ((IT) + 2) * 32, As[pw] + aoff0);               \
            GLOAD_LDS16(ap1 + ((IT) + 2) * 32, As[pw] + aoff1);               \
        }                                                                     \
        __builtin_amdgcn_sched_barrier(0);                                    \
        bf16x8 af[4], bf[4];                                                  \
        _Pragma("unroll")                                                     \
        for (int i = 0; i < 4; i++) {                                         \
            af[i] = *(const bf16x8*)(As[pA] + aRdOff + i * 16 * 32);          \
            int slotR = slotB0 ^ ((i + 4 * wn) & 3);                          \
            bf[i] = *(const bf16x8*)(Bs[RBUF] + bRdBase + i * 16 * BSTR + slotR * 8); \
        }                                                                     \
        _Pragma("unroll")                                                     \
        for (int mi = 0; mi < 4; mi++)                                        \
            _Pragma("unroll")                                                 \
            for (int nj = 0; nj < 4; nj++)                                    \
                acc[mi][nj] = __builtin_amdgcn_mfma_f32_16x16x32_bf16(        \
                    af[mi], bf[nj], acc[mi][nj], 0, 0, 0);                    \
        __builtin_amdgcn_sched_barrier(0);                                    \
        if ((IT) + 1 < NIT) BPACKS((RBUF) ^ 1, P0, P1, P2, P3);               \
        pA++; if (pA >= 3) pA = 0;                                            \
    }

    int pA = 0;
    for (int itb = 0; itb < NIT; itb += 2) {
        GITER(itb,     0, Fa0, Fa1, Fa2, Fa3, Fb0, Fb1, Fb2, Fb3);
        GITER(itb + 1, 1, Fb0, Fb1, Fb2, Fb3, Fa0, Fa1, Fa2, Fa3);
    }
#undef GITER
#undef BLOADS
#undef BPACKS

    // C/D layout (verified m89/m91): col = lane&15, row = quad*4 + reg
    if (SILU) {
#pragma unroll
        for (int mi = 0; mi < 4; mi++)
#pragma unroll
            for (int nj = 0; nj < 2; nj++) {
                f32x4 g = acc[mi][nj];
                f32x4 u = acc[mi][nj + 2];
#pragma unroll
                for (int r = 0; r < 4; r++) {
                    int rloc = wm * 64 + mi * 16 + quad * 4 + r;
                    if (rloc < rowsv) {
                        float gv = g[r], uv = u[r];
                        float a = (gv / (1.f + __expf(-gv))) * uv;   // silu(g)*u
                        int c = nt * 64 + wn * 32 + nj * 16 + mrow;
                        Cout[(size_t)(slotbase + m0 + rloc) * ID + c] = f2bf(a);
                    }
                }
            }
    } else {
#pragma unroll
        for (int mi = 0; mi < 4; mi++)
#pragma unroll
            for (int nj = 0; nj < 4; nj++) {
                f32x4 v = acc[mi][nj];
#pragma unroll
                for (int r = 0; r < 4; r++) {
                    int rloc = wm * 64 + mi * 16 + quad * 4 + r;
                    if (rloc < rowsv) {
                        int c = nt * 128 + wn * 64 + nj * 16 + mrow;
                        Cout[(size_t)(slotbase + m0 + rloc) * HD + c] = f2bf(v[r]);
                    }
                }
            }
    }
}

// ---------------- combine: out[t] = shared + sum_k w_k * eout[slot_k] ------
__global__ __launch_bounds__(256)
void k_combine(const unsigned short* __restrict__ eout,
               const int* __restrict__ smap,
               const float* __restrict__ wgt,
               float* __restrict__ out) {
    const int t = blockIdx.x;
    const int h0 = threadIdx.x * 4;
    ushort4 q = *(const ushort4*)(eout + (size_t)(SHARED_BASE + t) * HD + h0);
    float a0 = bf2f(q.x), a1 = bf2f(q.y), a2 = bf2f(q.z), a3 = bf2f(q.w);
#pragma unroll
    for (int r = 0; r < TOPK; r++) {
        int slot = smap[t * TOPK + r];
        if (slot >= 0) {
            float w = wgt[slot];
            ushort4 e4 = *(const ushort4*)(eout + (size_t)slot * HD + h0);
            a0 += w * bf2f(e4.x); a1 += w * bf2f(e4.y);
            a2 += w * bf2f(e4.z); a3 += w * bf2f(e4.w);
        }
    }
    float4 o; o.x = a0; o.y = a1; o.z = a2; o.w = a3;
    *(float4*)(out + (size_t)t * HD + h0) = o;
}

// ---------------- launch ----------------
// Workspace: xb 8 + act 36 + eout 72 + ~1.3 MB.
//   part (8 MB) aliases act: part written by logits, consumed by topk,
//   act written only later by GEMM1.
extern "C" void kernel_launch(void* const* d_in, const int* in_sizes, int n_in,
                              void* d_out, int out_size, void* d_ws, size_t ws_size,
                              hipStream_t stream) {
    const float* x   = (const float*)d_in[0];   // [T,H]
    const float* gw  = (const float*)d_in[1];   // [E,H]
    const float* wgu = (const float*)d_in[2];   // [E,H,2I]
    const float* wdn = (const float*)d_in[3];   // [E,I,H]
    const float* sgu = (const float*)d_in[4];   // [H,2I]
    const float* sdn = (const float*)d_in[5];   // [I,H]
    float* out = (float*)d_out;

    char* w = (char*)d_ws;
    size_t off = 0;
    int* cnt = (int*)(w + off);                       off += 256;
    unsigned short* xb   = (unsigned short*)(w + off); off += (size_t)TT * HD * 2;     // 8 MB
    unsigned short* act  = (unsigned short*)(w + off); off += (size_t)NSLOT * ID * 2;  // 36 MB
    unsigned short* eout = (unsigned short*)(w + off); off += (size_t)NSLOT * HD * 2;  // 72 MB
    int*   tok    = (int*)(w + off);   off += (size_t)NSLOT * 4;
    float* wgt    = (float*)(w + off); off += (size_t)NSLOT * 4;
    int*   smap   = (int*)(w + off);   off += (size_t)TT * TOPK * 4;
    int*   choice = (int*)(w + off);   off += (size_t)TT * TOPK * 4;
    float* cw     = (float*)(w + off); off += (size_t)TT * TOPK * 4;

    float* part = (float*)act;                        // alias: dead before GEMM1

    // router: split-K logits (+ fused x->bf16), top-4, slot scan
    k_logits<<<dim3(16, KSPLIT), 256, 0, stream>>>(x, gw, part, xb);
    k_topk<<<TT / 4, 256, 0, stream>>>(part, choice, cw, tok, wgt);
    k_assign<<<NEXP, 1024, 0, stream>>>(choice, cw, cnt, tok, wgt, smap);

    // GEMM1: gathered x @ gate_up^T (B = fp32 wgu direct), silu -> act
    k_moe_gemm<1024, true, true><<<dim3(8, MAXTILES), 256, 0, stream>>>(xb, wgu, sgu, act, tok, cnt);
    // GEMM2: act @ down^T (B = fp32 wdn direct) -> eout
    k_moe_gemm<512, false, false><<<dim3(8, MAXTILES), 256, 0, stream>>>(act, wdn, sdn, eout, tok, cnt);

    k_combine<<<TT, 256, 0, stream>>>(eout, smap, wgt, out);
}

// Round 18
// 395.975 us; speedup vs baseline: 1.1329x; 1.1329x over previous
//
#include <hip/hip_runtime.h>
#include <cstdint>
#include <cstddef>

// ---------------- problem constants ----------------
#define NEXP   32          // routed experts
#define TOPK   4
#define HD     1024        // hidden
#define ID     512         // intermediate
#define TT     4096        // tokens (B*S)
#define CAP    1024        // capacity per routed expert
#define SHARED_BASE (NEXP*CAP)        // 32768 : slot base of shared-expert rows
#define NSLOT  (NEXP*CAP + TT)        // 36864 total slot rows
#define MAXTILES 320       // grid-y: (qy>>3) up to 40 >= worst chunk 36

#define KSPLIT 16          // router split-K
#define KCH    64          // K per logits block
#define KSUB   16          // LDS sub-chunk

#define BSTR   40          // Bs row stride (elems): 80B -> bank-rich (R16)

typedef __attribute__((ext_vector_type(4))) float f32x4;
typedef __bf16 bf16x8 __attribute__((ext_vector_type(8)));

__device__ __forceinline__ unsigned short f2bf(float f) {
    union { float f; unsigned int u; } v; v.f = f;
    unsigned int u = v.u;
    u = (u + 0x7FFFu + ((u >> 16) & 1u)) >> 16;   // RNE
    return (unsigned short)u;
}
__device__ __forceinline__ float bf2f(unsigned short s) {
    union { unsigned int u; float f; } v; v.u = ((unsigned int)s) << 16;
    return v.f;
}

#define GLOAD_LDS16(g, l)                                                     \
    __builtin_amdgcn_global_load_lds(                                         \
        (__attribute__((address_space(1))) void*)(g),                         \
        (__attribute__((address_space(3))) void*)(l), 16, 0, 0)

// ---------------- router logits (split-K) + fused x->bf16 convert ---------
__global__ __launch_bounds__(256)
void k_logits(const float* __restrict__ x, const float* __restrict__ gw,
              float* __restrict__ part, unsigned short* __restrict__ xb) {
    __shared__ float xsT[KSUB][260];
    __shared__ float gsT[KSUB][36];
    const int tid = threadIdx.x;
    const int lane = tid & 63, wv = tid >> 6;
    const int tg = lane >> 2, eg = lane & 3;
    const int t0 = blockIdx.x * 256;
    const int kbase = blockIdx.y * KCH;
    const int tbase = wv * 64 + tg * 4;
    const int ebase = eg * 8;

    float acc[4][8];
#pragma unroll
    for (int j = 0; j < 4; j++)
#pragma unroll
        for (int i = 0; i < 8; i++) acc[j][i] = 0.f;

    for (int ks = 0; ks < KCH; ks += KSUB) {
        const int k0 = kbase + ks;
        if (ks > 0) __syncthreads();
        // stage x sub-chunk [256 t][16 k] (+ bf16 copy); 2-way banks (free)
#pragma unroll
        for (int p = 0; p < 4; p++) {
            int vid = p * 256 + tid;
            int t = vid >> 2, kq = (vid & 3) * 4;
            float4 v = *(const float4*)(x + (size_t)(t0 + t) * HD + k0 + kq);
            xsT[kq + 0][t] = v.x; xsT[kq + 1][t] = v.y;
            xsT[kq + 2][t] = v.z; xsT[kq + 3][t] = v.w;
            ushort4 o;
            o.x = f2bf(v.x); o.y = f2bf(v.y); o.z = f2bf(v.z); o.w = f2bf(v.w);
            *(ushort4*)(xb + (size_t)(t0 + t) * HD + k0 + kq) = o;
        }
#pragma unroll
        for (int p = 0; p < 2; p++) {
            int vid = p * 256 + tid;
            int e = vid >> 4, k = vid & 15;
            gsT[k][e] = gw[(size_t)e * HD + k0 + k];
        }
        __syncthreads();
#pragma unroll 4
        for (int k = 0; k < KSUB; k++) {
            float4 xv = *(const float4*)&xsT[k][tbase];
            float4 g0 = *(const float4*)&gsT[k][ebase];
            float4 g1 = *(const float4*)&gsT[k][ebase + 4];
            float xa[4] = {xv.x, xv.y, xv.z, xv.w};
#pragma unroll
            for (int j = 0; j < 4; j++) {
                acc[j][0] += xa[j] * g0.x; acc[j][1] += xa[j] * g0.y;
                acc[j][2] += xa[j] * g0.z; acc[j][3] += xa[j] * g0.w;
                acc[j][4] += xa[j] * g1.x; acc[j][5] += xa[j] * g1.y;
                acc[j][6] += xa[j] * g1.z; acc[j][7] += xa[j] * g1.w;
            }
        }
    }
    const size_t base = ((size_t)blockIdx.y * TT + (t0 + tbase)) * 32 + ebase;
#pragma unroll
    for (int j = 0; j < 4; j++) {
        float4 w0, w1;
        w0.x = acc[j][0]; w0.y = acc[j][1]; w0.z = acc[j][2]; w0.w = acc[j][3];
        w1.x = acc[j][4]; w1.y = acc[j][5]; w1.z = acc[j][6]; w1.w = acc[j][7];
        *(float4*)(part + base + (size_t)j * 32) = w0;
        *(float4*)(part + base + (size_t)j * 32 + 4) = w1;
    }
}

// ---------------- router part 2: reduce partials, top-4 (NO atomics) ------
__global__ __launch_bounds__(256)
void k_topk(const float* __restrict__ part,
            int* __restrict__ choice, float* __restrict__ cw,
            int* __restrict__ tok, float* __restrict__ wgt) {
    const int lane = threadIdx.x & 63, wv = threadIdx.x >> 6;
    const int t = blockIdx.x * 4 + wv;
    const int e = lane & 31;
    const int sbase = (lane >> 5) * 8;
    float v = 0.f;
#pragma unroll
    for (int s = 0; s < 8; s++)
        v += part[((size_t)(sbase + s) * TT + t) * 32 + e];
    v += __shfl_xor(v, 32);
    float sc = (lane < 32) ? v : -INFINITY;

    float lv[TOPK]; int le[TOPK];
#pragma unroll
    for (int r = 0; r < TOPK; r++) {
        float m = sc;
#pragma unroll
        for (int d = 1; d < 64; d <<= 1) m = fmaxf(m, __shfl_xor(m, d));
        unsigned long long ball = __ballot(sc == m);
        int widx = __ffsll(ball) - 1;       // lowest lane on tie = jax top_k
        lv[r] = m; le[r] = widx;
        if (lane == widx) sc = -INFINITY;
    }
    if (lane == 0) {
        float wv4[TOPK], wsum = 0.f;
#pragma unroll
        for (int r = 0; r < TOPK; r++) { wv4[r] = __expf(lv[r] - lv[0]); wsum += wv4[r]; }
#pragma unroll
        for (int r = 0; r < TOPK; r++) {
            choice[t * TOPK + r] = le[r];
            cw[t * TOPK + r] = wv4[r] / wsum;
        }
        tok[SHARED_BASE + t] = t;            // shared-expert identity slot
        wgt[SHARED_BASE + t] = 1.0f;
    }
}

// ---------------- slot assignment: token-granular ballot-scan -------------
__global__ __launch_bounds__(1024)
void k_assign(const int* __restrict__ choice, const float* __restrict__ cw,
              int* __restrict__ cnt, int* __restrict__ tok,
              float* __restrict__ wgt, int* __restrict__ smap) {
    const int e = blockIdx.x;
    const int tid = threadIdx.x, lane = tid & 63, wv = tid >> 6;
    __shared__ int wtot[16];
    int running = 0;
    for (int it = 0; it < TT / 1024; it++) {       // 4 iterations
        const int t = it * 1024 + tid;             // token id
        const int4   c4 = *(const int4*)(choice + t * 4);
        const float4 w4 = *(const float4*)(cw + t * 4);
        unsigned m = (unsigned)(c4.x == e) | ((unsigned)(c4.y == e) << 1)
                   | ((unsigned)(c4.z == e) << 2) | ((unsigned)(c4.w == e) << 3);
        int mc = __popc(m);
        int pre = mc;                              // inclusive wave scan
#pragma unroll
        for (int d = 1; d < 64; d <<= 1) {
            int up = __shfl_up(pre, d);
            if (lane >= d) pre += up;
        }
        if (lane == 63) wtot[wv] = pre;            // wave total
        const int wpre = pre - mc;                 // exclusive within wave
        __syncthreads();
        int woff = 0, tot = 0;
#pragma unroll
        for (int w = 0; w < 16; w++) { int c = wtot[w]; tot += c; if (w < wv) woff += c; }
        int base = running + woff + wpre;
        running += tot;
        __syncthreads();
        if (m) {
            const float wa[4] = {w4.x, w4.y, w4.z, w4.w};
            int k = 0;
#pragma unroll
            for (int r = 0; r < 4; r++) {
                if (m & (1u << r)) {
                    int pos = base + k;
                    int i = t * 4 + r;
                    if (pos < CAP) {
                        int slot = e * CAP + pos;
                        tok[slot] = t;
                        wgt[slot] = wa[r];
                        smap[i] = slot;
                    } else {
                        smap[i] = -1;              // overflow dropped (P ~ 0)
                    }
                    k++;
                }
            }
        }
    }
    if (tid == 0) cnt[e] = min(running, CAP);
}

// ---------------- grouped GEMM: 128x128 tile, BK=32 ----------------------
// R18: full-iteration B cover at ZERO register cost. R17 proved the 2nd
// reg set kills occupancy (VGPR 112 -> 2 waves/SIMD -> 160us). Instead,
// BLOAD moves to IMMEDIATELY AFTER BPACK (when the F regs die): F for
// chunk c is loaded at end of iter c-2, consumed by BPACK at end of iter
// c-1 -> cover ~1 full iter (~1500 cyc > 900 HBM) with the SAME registers.
// Queue trace (steady, verified incl. prologue/it0/tail): at BPACK the
// compiler reg-dep wait is vmcnt(2) (younger = 2 A-gloads), which also
// drains that iter's A gload_lds (older than the B loads). Top-of-iter
// wait relaxes to vmcnt(6)+lgkmcnt(0): steady-state no-op (6 in flight =
// A(it+1) 2 + B(it+1) 4); iter-0 case drains A(0) (8 -> 6). Buffer
// hazards identical to R16 (only the pure-register BLOAD moved).
// BSTR=40 + slot XOR F(r)=((r>>2)&3)^((r>>4)&3) kept (4-way writes, R16).
// LDS 24 + 20.5 = 44.5 KB; ~80 VGPR -> 3 waves/SIMD.
template <int KD, bool GATHER, bool SILU>
__global__ __launch_bounds__(256)
void k_moe_gemm(const unsigned short* __restrict__ Ab,
                const float* __restrict__ Bf,
                const float* __restrict__ BfS,
                unsigned short* __restrict__ Cout,
                const int* __restrict__ tok,
                const int* __restrict__ cnt) {
    const int tid  = threadIdx.x;
    const int lane = tid & 63;
    const int wv   = tid >> 6;

    // ---- in-kernel tile table ----
    int c_l = (lane < NEXP) ? min(cnt[lane], CAP) : ((lane == NEXP) ? TT : 0);
    int nt_l = (c_l + 127) >> 7;
    int pre = nt_l;
#pragma unroll
    for (int d = 1; d < 64; d <<= 1) {
        int up = __shfl_up(pre, d);
        if (lane >= d) pre += up;
    }
    const int ntl = __shfl(pre, 63);
    const int chunk = (ntl + 7) >> 3;
    const int c_xcd = blockIdx.x;
    const int qy = blockIdx.y;
    if ((qy >> 3) >= chunk) return;
    const int j = c_xcd * chunk + (qy >> 3);
    if (j >= ntl) return;
    const int nt = qy & 7;
    const int start_l = pre - nt_l;
    const bool mine = (j >= start_l) && (j < start_l + nt_l);
    const unsigned long long bl = __ballot(mine);
    const int e_lane = __ffsll((long long)bl) - 1;
    const int e  = e_lane;
    const int mt = j - __shfl(start_l, e_lane);
    const int cE = __shfl(c_l, e_lane);

    const int slotbase = (e < NEXP) ? e * CAP : SHARED_BASE;
    const int m0 = mt * 128;
    const int rowsv = min(128, cE - m0);

    const float* Btf = (e < NEXP) ? Bf + (size_t)e * ((size_t)KD * 1024) : BfS;

    __shared__ unsigned short As[3][128 * 32];   // 24 KB
    __shared__ unsigned short Bs[2][128 * BSTR]; // 20.5 KB

    // ---- A staging (gload_lds; swizzle s^((r>>2)&3) on lane map) ----
    const int rr   = lane >> 2;
    const int segA = (lane & 3) ^ ((lane >> 4) & 3);
    const int r0 = wv * 32 + rr;
    const int r1 = r0 + 16;

    int ga0 = m0 + r0, ga1 = m0 + r1;
    int ra0, ra1;
    if (GATHER) {
        ra0 = (ga0 < cE) ? tok[slotbase + ga0] : 0;
        ra1 = (ga1 < cE) ? tok[slotbase + ga1] : 0;
    } else {
        ra0 = slotbase + ga0;
        ra1 = slotbase + ga1;
    }
    const unsigned short* ap0 = Ab + (size_t)ra0 * KD + segA * 8;
    const unsigned short* ap1 = Ab + (size_t)ra1 * KD + segA * 8;
    const int aoff0 = (wv * 32) * 32, aoff1 = (wv * 32 + 16) * 32;

    // ---- B staging lane map: hB = lane>>5, nw = lane&31 (4-col window) ----
    const int hB = lane >> 5;                 // k-half within wave's 8 rows
    const int nw = lane & 31;                 // col window: 4 cols
    int rB[4], offB[4];
    int bcol;
    if (SILU) {
        const int sn0 = nw * 4;
        const int side = sn0 >> 6;            // window never straddles 64
        const int jj0 = sn0 & 63;
        bcol = (side ? 512 : 0) + nt * 64 + jj0;
#pragma unroll
        for (int q = 0; q < 4; q++) {
            int jj = jj0 + q;
            rB[q] = ((jj >> 5) << 6) + (side << 5) + (jj & 31);
        }
    } else {
        bcol = nt * 128 + nw * 4;
#pragma unroll
        for (int q = 0; q < 4; q++) rB[q] = nw * 4 + q;
    }
#pragma unroll
    for (int q = 0; q < 4; q++) {
        int slotW = wv ^ ((rB[q] >> 2) & 3) ^ ((rB[q] >> 4) & 3);
        offB[q] = rB[q] * BSTR + slotW * 8 + hB * 4;   // elems; 8B-aligned
    }
    // global src base: fp32 rows (k0 + wv*8 + hB*4 + d), stride 1024 floats
    const float* bpf = Btf + (size_t)(wv * 8 + hB * 4) * 1024 + bcol;

    float4 F0, F1, F2, F3;        // single B reg set, reused right after BPACK
#define BLOAD(IT)                                                             \
    {                                                                         \
        const float* bpk = bpf + (size_t)(IT) * 32 * 1024;                    \
        F0 = *(const float4*)(bpk);                                           \
        F1 = *(const float4*)(bpk + 1024);                                    \
        F2 = *(const float4*)(bpk + 2048);                                    \
        F3 = *(const float4*)(bpk + 3072);                                    \
    }
#define BPACK(BUF)                                                            \
    {                                                                         \
        unsigned short* bw = &Bs[BUF][0];                                     \
        const float* a0p = (const float*)&F0;                                 \
        const float* a1p = (const float*)&F1;                                 \
        const float* a2p = (const float*)&F2;                                 \
        const float* a3p = (const float*)&F3;                                 \
        _Pragma("unroll")                                                     \
        for (int q = 0; q < 4; q++) {                                         \
            unsigned lo, hi;                                                  \
            asm("v_cvt_pk_bf16_f32 %0, %1, %2"                                \
                : "=v"(lo) : "v"(a0p[q]), "v"(a1p[q]));                       \
            asm("v_cvt_pk_bf16_f32 %0, %1, %2"                                \
                : "=v"(hi) : "v"(a2p[q]), "v"(a3p[q]));                       \
            uint2 wv2; wv2.x = lo; wv2.y = hi;                                \
            *(uint2*)(bw + offB[q]) = wv2;                                    \
        }                                                                     \
    }

    f32x4 acc[4][4];
#pragma unroll
    for (int i = 0; i < 4; i++)
#pragma unroll
        for (int j2 = 0; j2 < 4; j2++) acc[i][j2] = (f32x4)(0.0f);

    const int mrow = lane & 15;
    const int quad = lane >> 4;
    const int wm = wv >> 1, wn = wv & 1;
    const int swA = (quad ^ ((mrow >> 2) & 3)) * 8;      // A read slot
    const int aRdOff = (wm * 64 + mrow) * 32 + swA;
    const int bRdBase = (wn * 64 + mrow) * BSTR;         // B read base (row part)
    const int slotB0 = quad ^ ((mrow >> 2) & 3);         // B slot before i-term

    const int NIT = KD / 32;

    // ---- prologue: B(0)->F, A(0),A(1) gloads, pack B(0), B(1)->F ----
    BLOAD(0);
    __builtin_amdgcn_sched_barrier(0);
    GLOAD_LDS16(ap0, As[0] + aoff0);
    GLOAD_LDS16(ap1, As[0] + aoff1);
    GLOAD_LDS16(ap0 + 32, As[1] + aoff0);
    GLOAD_LDS16(ap1 + 32, As[1] + aoff1);
    __builtin_amdgcn_sched_barrier(0);
    BPACK(0);                      // waits B(0) only (vmcnt(4)); A stays in flight
    BLOAD(1);                      // B(1) in flight across ALL of iter 0

    int pA = 0, pB = 0;
    for (int it = 0; it < NIT; ++it) {
        // steady state: 6 in flight (A(it+1) 2 + B(it+1) 4) -> no-op wait;
        // iter 0: drains A(0) (8 -> 6). lgkmcnt(0) orders prior ds_writes.
        asm volatile("s_waitcnt vmcnt(6) lgkmcnt(0)" ::: "memory");
        __builtin_amdgcn_s_barrier();
        asm volatile("" ::: "memory");

        const bool hasA = (it + 2) < NIT;
        if (hasA) {
            int pw = pA + 2; if (pw >= 3) pw -= 3;
            GLOAD_LDS16(ap0 + (it + 2) * 32, As[pw] + aoff0);
            GLOAD_LDS16(ap1 + (it + 2) * 32, As[pw] + aoff1);
        }
        __builtin_amdgcn_sched_barrier(0);

        bf16x8 af[4], bf[4];
#pragma unroll
        for (int i = 0; i < 4; i++) {
            af[i] = *(const bf16x8*)(As[pA] + aRdOff + i * 16 * 32);
            int slotR = slotB0 ^ ((i + 4 * wn) & 3);     // F(r) i-term
            bf[i] = *(const bf16x8*)(Bs[pB] + bRdBase + i * 16 * BSTR + slotR * 8);
        }
#pragma unroll
        for (int mi = 0; mi < 4; mi++)
#pragma unroll
            for (int nj = 0; nj < 4; nj++)
                acc[mi][nj] = __builtin_amdgcn_mfma_f32_16x16x32_bf16(
                    af[mi], bf[nj], acc[mi][nj], 0, 0, 0);
        __builtin_amdgcn_sched_barrier(0);
        if (it + 1 < NIT) {
            BPACK(pB ^ 1);         // consumes F=B(it+1); reg-dep wait vmcnt(2)
                                   // drains this iter's A gloads too (older)
            if (it + 2 < NIT) BLOAD(it + 2);   // refill F immediately: full-iter cover
        }
        pA++; if (pA >= 3) pA = 0;
        pB ^= 1;
    }
#undef BLOAD
#undef BPACK

    // C/D layout (verified m89/m91): col = lane&15, row = quad*4 + reg
    if (SILU) {
#pragma unroll
        for (int mi = 0; mi < 4; mi++)
#pragma unroll
            for (int nj = 0; nj < 2; nj++) {
                f32x4 g = acc[mi][nj];
                f32x4 u = acc[mi][nj + 2];
#pragma unroll
                for (int r = 0; r < 4; r++) {
                    int rloc = wm * 64 + mi * 16 + quad * 4 + r;
                    if (rloc < rowsv) {
                        float gv = g[r], uv = u[r];
                        float a = (gv / (1.f + __expf(-gv))) * uv;   // silu(g)*u
                        int c = nt * 64 + wn * 32 + nj * 16 + mrow;
                        Cout[(size_t)(slotbase + m0 + rloc) * ID + c] = f2bf(a);
                    }
                }
            }
    } else {
#pragma unroll
        for (int mi = 0; mi < 4; mi++)
#pragma unroll
            for (int nj = 0; nj < 4; nj++) {
                f32x4 v = acc[mi][nj];
#pragma unroll
                for (int r = 0; r < 4; r++) {
                    int rloc = wm * 64 + mi * 16 + quad * 4 + r;
                    if (rloc < rowsv) {
                        int c = nt * 128 + wn * 64 + nj * 16 + mrow;
                        Cout[(size_t)(slotbase + m0 + rloc) * HD + c] = f2bf(v[r]);
                    }
                }
            }
    }
}

// ---------------- combine: out[t] = shared + sum_k w_k * eout[slot_k] ------
__global__ __launch_bounds__(256)
void k_combine(const unsigned short* __restrict__ eout,
               const int* __restrict__ smap,
               const float* __restrict__ wgt,
               float* __restrict__ out) {
    const int t = blockIdx.x;
    const int h0 = threadIdx.x * 4;
    ushort4 q = *(const ushort4*)(eout + (size_t)(SHARED_BASE + t) * HD + h0);
    float a0 = bf2f(q.x), a1 = bf2f(q.y), a2 = bf2f(q.z), a3 = bf2f(q.w);
#pragma unroll
    for (int r = 0; r < TOPK; r++) {
        int slot = smap[t * TOPK + r];
        if (slot >= 0) {
            float w = wgt[slot];
            ushort4 e4 = *(const ushort4*)(eout + (size_t)slot * HD + h0);
            a0 += w * bf2f(e4.x); a1 += w * bf2f(e4.y);
            a2 += w * bf2f(e4.z); a3 += w * bf2f(e4.w);
        }
    }
    float4 o; o.x = a0; o.y = a1; o.z = a2; o.w = a3;
    *(float4*)(out + (size_t)t * HD + h0) = o;
}

// ---------------- launch ----------------
// Workspace: xb 8 + act 36 + eout 72 + ~1.3 MB.
//   part (8 MB) aliases act: part written by logits, consumed by topk,
//   act written only later by GEMM1.
extern "C" void kernel_launch(void* const* d_in, const int* in_sizes, int n_in,
                              void* d_out, int out_size, void* d_ws, size_t ws_size,
                              hipStream_t stream) {
    const float* x   = (const float*)d_in[0];   // [T,H]
    const float* gw  = (const float*)d_in[1];   // [E,H]
    const float* wgu = (const float*)d_in[2];   // [E,H,2I]
    const float* wdn = (const float*)d_in[3];   // [E,I,H]
    const float* sgu = (const float*)d_in[4];   // [H,2I]
    const float* sdn = (const float*)d_in[5];   // [I,H]
    float* out = (float*)d_out;

    char* w = (char*)d_ws;
    size_t off = 0;
    int* cnt = (int*)(w + off);                       off += 256;
    unsigned short* xb   = (unsigned short*)(w + off); off += (size_t)TT * HD * 2;     // 8 MB
    unsigned short* act  = (unsigned short*)(w + off); off += (size_t)NSLOT * ID * 2;  // 36 MB
    unsigned short* eout = (unsigned short*)(w + off); off += (size_t)NSLOT * HD * 2;  // 72 MB
    int*   tok    = (int*)(w + off);   off += (size_t)NSLOT * 4;
    float* wgt    = (float*)(w + off); off += (size_t)NSLOT * 4;
    int*   smap   = (int*)(w + off);   off += (size_t)TT * TOPK * 4;
    int*   choice = (int*)(w + off);   off += (size_t)TT * TOPK * 4;
    float* cw     = (float*)(w + off); off += (size_t)TT * TOPK * 4;

    float* part = (float*)act;                        // alias: dead before GEMM1

    // router: split-K logits (+ fused x->bf16), top-4, slot scan
    k_logits<<<dim3(16, KSPLIT), 256, 0, stream>>>(x, gw, part, xb);
    k_topk<<<TT / 4, 256, 0, stream>>>(part, choice, cw, tok, wgt);
    k_assign<<<NEXP, 1024, 0, stream>>>(choice, cw, cnt, tok, wgt, smap);

    // GEMM1: gathered x @ gate_up^T (B = fp32 wgu direct), silu -> act
    k_moe_gemm<1024, true, true><<<dim3(8, MAXTILES), 256, 0, stream>>>(xb, wgu, sgu, act, tok, cnt);
    // GEMM2: act @ down^T (B = fp32 wdn direct) -> eout
    k_moe_gemm<512, false, false><<<dim3(8, MAXTILES), 256, 0, stream>>>(act, wdn, sdn, eout, tok, cnt);

    k_combine<<<TT, 256, 0, stream>>>(eout, smap, wgt, out);
}